// Round 9
// baseline (319.124 us; speedup 1.0000x reference)
//
#include <hip/hip_runtime.h>

// MultiQueryAttention: B=2, S=2048, E=1024, H=16, D=64. fp32 I/O.
#define E_DIM  1024
#define H_HEADS 16
#define D_HEAD  64
#define B_BATCH 2
#define S_SEQ  2048
#define M_ROWS (B_BATCH * S_SEQ)   // 4096

typedef unsigned short u16;
typedef unsigned int   u32;
typedef __attribute__((ext_vector_type(8))) short bf16x8;
typedef __attribute__((ext_vector_type(4))) short bf16x4;
typedef __attribute__((ext_vector_type(4))) float f32x4;

#define MFMA32(a, b, c) __builtin_amdgcn_mfma_f32_16x16x32_bf16(a, b, c, 0, 0, 0)

#if __has_builtin(__builtin_amdgcn_mfma_f32_16x16x16bf16_1k)
#define HAVE_MFMA16 1
#define MFMA16(a, b, c) __builtin_amdgcn_mfma_f32_16x16x16bf16_1k(a, b, c, 0, 0, 0)
#else
#define HAVE_MFMA16 0
#endif

__device__ __forceinline__ u16 f2bf(float f) {
    union { float f; u32 i; } x; x.f = f;
    u32 r = x.i + 0x7fffu + ((x.i >> 16) & 1u);   // RNE (finite inputs)
    return (u16)(r >> 16);
}

#if __has_builtin(__builtin_amdgcn_cvt_pk_bf16_f32)
typedef __attribute__((ext_vector_type(2))) __bf16 bfp2;
__device__ __forceinline__ u32 pk2(float a, float b) {
    bfp2 t = __builtin_amdgcn_cvt_pk_bf16_f32(a, b);
    union { bfp2 v; u32 u; } c; c.v = t; return c.u;
}
#else
__device__ __forceinline__ u32 pk2(float a, float b) {
    return (u32)f2bf(a) | ((u32)f2bf(b) << 16);
}
#endif

__device__ __forceinline__ bf16x8 cvt8(const float4& a, const float4& b) {
    union { u32 u[4]; bf16x8 v; } t;
    t.u[0] = pk2(a.x, a.y); t.u[1] = pk2(a.z, a.w);
    t.u[2] = pk2(b.x, b.y); t.u[3] = pk2(b.z, b.w);
    return t.v;
}
__device__ __forceinline__ bf16x4 pack4(const f32x4& v) {
    union { u32 u[2]; bf16x4 w; } t;
    t.u[0] = pk2(v[0], v[1]); t.u[1] = pk2(v[2], v[3]);
    return t.w;
}

// async global->LDS, 16B/lane. LDS dest must be wave-uniform base + lane*16.
__device__ __forceinline__ void gl_lds16(const u16* g, u16* l) {
    __builtin_amdgcn_global_load_lds(
        (const __attribute__((address_space(1))) u32*)g,
        (__attribute__((address_space(3))) u32*)l, 16, 0, 0);
}

// ---------------------------------------------------------------------------
// All four weight casts in one dispatch.
// ---------------------------------------------------------------------------
__global__ __launch_bounds__(256) void cast_all_kernel(
    const float* __restrict__ Wq, const float* __restrict__ Wo,
    const float* __restrict__ Wk, const float* __restrict__ Wv,
    u16* __restrict__ wq, u16* __restrict__ wo,
    u16* __restrict__ wk, u16* __restrict__ wv)
{
    const int NQ = E_DIM * E_DIM / 4;
    const int NK = D_HEAD * E_DIM / 4;
    int i = blockIdx.x * 256 + threadIdx.x;
    const float* s; u16* d; int j;
    if (i < NQ)               { s = Wq; d = wq; j = i; }
    else if (i < 2 * NQ)      { s = Wo; d = wo; j = i - NQ; }
    else if (i < 2 * NQ + NK) { s = Wk; d = wk; j = i - 2 * NQ; }
    else                      { s = Wv; d = wv; j = i - 2 * NQ - NK; }
    float4 v = ((const float4*)s)[j];
    ushort4 o;
    o.x = f2bf(v.x); o.y = f2bf(v.y); o.z = f2bf(v.z); o.w = f2bf(v.w);
    ((ushort4*)d)[j] = o;
}

// ---------------------------------------------------------------------------
// Split-K MFMA GEMM. Tile 64(M)x128(N), BK=32, dbuf single-barrier loop.
// Grid (N/128, M/64, KS): KS=2 -> 1024 blocks = 4 blocks/CU.
// MODE 0: store (acc + bias)*scale as bf16 (requires KS=1).
// MODE 1: atomicAdd fp32 acc*scale (+ bias*scale from the kz==0 half) into Cv
//         (Cv must be zeroed before launch; split halves race benignly).
// A: [M,K] fp32 (reg-cast staging) or bf16 (global_load_lds). W: [N,K] bf16.
// ---------------------------------------------------------------------------
template<typename TA, int MODE>
__global__ __launch_bounds__(256, 4) void gemm_splitk_kernel(
    const TA* __restrict__ A, const u16* __restrict__ W,
    const float* __restrict__ bias, void* __restrict__ Cv,
    int M, int N, int K, int Ksub, float scale)
{
    __shared__ u16 Asm[2][64 * 32];
    __shared__ u16 Bsm[2][128 * 32];

    const int tid = threadIdx.x;
    const int w  = tid >> 6;
    const int ln = tid & 63;
    const int n  = ln & 15;
    const int qd = ln >> 4;
    const int lr = ln >> 2;
    const int c8 = (ln & 3) * 8;
    const int wm = (w & 1) * 32;
    const int wn = (w >> 1) * 64;

    const int m0 = blockIdx.y * 64;
    const int n0 = blockIdx.x * 128;
    const int kz = blockIdx.z;
    const int kbeg = kz * Ksub;
    const int kend = kbeg + Ksub;

    const int arow = w * 16 + lr;    // 0..63

    f32x4 acc[2][4];
#pragma unroll
    for (int mt = 0; mt < 2; mt++)
#pragma unroll
        for (int nt = 0; nt < 4; nt++) acc[mt][nt] = (f32x4){0.f, 0.f, 0.f, 0.f};

    auto stageB = [&](int p, int k0) {
#pragma unroll
        for (int j = 0; j < 2; j++) {
            int row = w * 32 + j * 16 + lr;
            gl_lds16(W + (size_t)(n0 + row) * K + k0 + c8, &Bsm[p][row * 32 + c8]);
        }
    };
    auto compute = [&](int p) {
        bf16x8 af[2], bfr[4];
#pragma unroll
        for (int t = 0; t < 2; t++)
            af[t] = *(const bf16x8*)&Asm[p][(wm + t * 16 + n) * 32 + qd * 8];
#pragma unroll
        for (int t = 0; t < 4; t++)
            bfr[t] = *(const bf16x8*)&Bsm[p][(wn + t * 16 + n) * 32 + qd * 8];
#pragma unroll
        for (int mt = 0; mt < 2; mt++)
#pragma unroll
            for (int nt = 0; nt < 4; nt++)
                acc[mt][nt] = MFMA32(af[mt], bfr[nt], acc[mt][nt]);
    };

    // prologue
    if constexpr (sizeof(TA) == 4) {
        const float* pa = (const float*)A + (size_t)(m0 + arow) * K + kbeg + c8;
        float4 a0 = ((const float4*)pa)[0], a1 = ((const float4*)pa)[1];
        *(bf16x8*)&Asm[0][arow * 32 + c8] = cvt8(a0, a1);
    } else {
        gl_lds16((const u16*)A + (size_t)(m0 + arow) * K + kbeg + c8,
                 &Asm[0][arow * 32 + c8]);
    }
    stageB(0, kbeg);

    int p = 0;
    for (int k0 = kbeg + 32; k0 < kend; k0 += 32) {
        __syncthreads();
        if constexpr (sizeof(TA) == 4) {
            const float* pa = (const float*)A + (size_t)(m0 + arow) * K + k0 + c8;
            float4 a0 = ((const float4*)pa)[0], a1 = ((const float4*)pa)[1];
            stageB(p ^ 1, k0);
            compute(p);
            *(bf16x8*)&Asm[p ^ 1][arow * 32 + c8] = cvt8(a0, a1);
        } else {
            gl_lds16((const u16*)A + (size_t)(m0 + arow) * K + k0 + c8,
                     &Asm[p ^ 1][arow * 32 + c8]);
            stageB(p ^ 1, k0);
            compute(p);
        }
        p ^= 1;
    }
    __syncthreads();
    compute(p);

    float bb[4];
#pragma unroll
    for (int nt = 0; nt < 4; nt++)
        bb[nt] = (kz == 0) ? bias[n0 + wn + nt * 16 + n] * scale : 0.f;

#pragma unroll
    for (int mt = 0; mt < 2; mt++)
#pragma unroll
        for (int r = 0; r < 4; r++) {
            const int row = m0 + wm + mt * 16 + qd * 4 + r;
#pragma unroll
            for (int nt = 0; nt < 4; nt++) {
                const int col = n0 + wn + nt * 16 + n;
                float v = acc[mt][nt][r] * scale + bb[nt];
                if (MODE == 1)
                    atomicAdd(&((float*)Cv)[(size_t)row * N + col], v);
                else
                    ((u16*)Cv)[(size_t)row * N + col] = f2bf(v);
            }
        }
}

// ---------------------------------------------------------------------------
// Fused K/V projection (round-6 LDS-staged form). blockIdx.y==0 -> K proj
// (row-major), ==1 -> V proj (transposed out V^T[64][M]). Tile 64x64, BK=32.
// ---------------------------------------------------------------------------
__global__ __launch_bounds__(256) void kv_proj_kernel(
    const float* __restrict__ key, const float* __restrict__ value,
    const u16* __restrict__ Wk, const u16* __restrict__ Wv,
    const float* __restrict__ bk, const float* __restrict__ bv,
    u16* __restrict__ Kout, u16* __restrict__ VTout, int M, int K)
{
    const bool vproj = (blockIdx.y == 1);
    const float* A    = vproj ? value : key;
    const u16*  W     = vproj ? Wv : Wk;
    const float* bias = vproj ? bv : bk;

    __shared__ u16 Asm[64 * 32];
    __shared__ u16 Bsm[64 * 32];

    const int tid = threadIdx.x;
    const int w  = tid >> 6;
    const int ln = tid & 63;
    const int n  = ln & 15;
    const int qd = ln >> 4;
    const int wm = (w & 1) * 32;
    const int wn = (w >> 1) * 32;
    const int m0 = blockIdx.x * 64;

    const int srow = tid >> 2;
    const int scol = (tid & 3) * 8;

    f32x4 acc[2][2];
#pragma unroll
    for (int mt = 0; mt < 2; mt++)
#pragma unroll
        for (int nt = 0; nt < 2; nt++) acc[mt][nt] = (f32x4){0.f, 0.f, 0.f, 0.f};

    for (int k0 = 0; k0 < K; k0 += 32) {
        __syncthreads();
        const float* pa = A + (size_t)(m0 + srow) * K + k0 + scol;
        float4 a0 = ((const float4*)pa)[0], a1 = ((const float4*)pa)[1];
        *(bf16x8*)&Asm[srow * 32 + scol] = cvt8(a0, a1);
        gl_lds16(W + (size_t)srow * K + k0 + scol, &Bsm[srow * 32 + scol]);
        __syncthreads();

        bf16x8 af[2], bfr[2];
#pragma unroll
        for (int t = 0; t < 2; t++) {
            af[t]  = *(const bf16x8*)&Asm[(wm + t * 16 + n) * 32 + qd * 8];
            bfr[t] = *(const bf16x8*)&Bsm[(wn + t * 16 + n) * 32 + qd * 8];
        }
#pragma unroll
        for (int mt = 0; mt < 2; mt++)
#pragma unroll
            for (int nt = 0; nt < 2; nt++)
                acc[mt][nt] = MFMA32(af[mt], bfr[nt], acc[mt][nt]);
    }

    if (!vproj) {
#pragma unroll
        for (int mt = 0; mt < 2; mt++)
#pragma unroll
            for (int r = 0; r < 4; r++) {
                const int row = m0 + wm + mt * 16 + qd * 4 + r;
#pragma unroll
                for (int nt = 0; nt < 2; nt++) {
                    const int col = wn + nt * 16 + n;
                    Kout[(size_t)row * 64 + col] = f2bf(acc[mt][nt][r] + bias[col]);
                }
            }
    } else {
#pragma unroll
        for (int mt = 0; mt < 2; mt++)
#pragma unroll
            for (int nt = 0; nt < 2; nt++) {
                const int col = wn + nt * 16 + n;
                const int row0 = m0 + wm + mt * 16 + qd * 4;
                float b4 = bias[col];
                ushort4 pk;
                pk.x = f2bf(acc[mt][nt][0] + b4);
                pk.y = f2bf(acc[mt][nt][1] + b4);
                pk.z = f2bf(acc[mt][nt][2] + b4);
                pk.w = f2bf(acc[mt][nt][3] + b4);
                *(ushort4*)&VTout[(size_t)col * M + row0] = pk;
            }
    }
}

// ---------------------------------------------------------------------------
// MFMA flash MQA attention v5: round-7 structure (q-tile 128, MFMA16 PV) +
// K/V double-buffering (stage s0+128 before computing s0) + exp2 softmax
// (log2e folded into Q scale) + linear (round-6) LDS staging, no swizzle.
// QT = float (q fp32, pre-scaled) or u16 (q bf16). O bf16 (may alias bf16 Q).
// Block 256 = 4 waves; grid 512 = 2 blocks/CU; LDS 64 KB (2 bufs).
// ---------------------------------------------------------------------------
template<typename QT>
__global__ __launch_bounds__(256, 2) void mqa_attn_kernel(
    const QT* Q, const u16* __restrict__ K,
    const u16* __restrict__ VT, u16* O)
{
    __shared__ u16 ksm[2][2][128 * 32];   // [buf][k-half][row][32]
    __shared__ u16 vsm[2][4][64 * 32];    // [buf][s-chunk32][d][32]
#if !HAVE_MFMA16
    __shared__ u16 psm[4][32 * 128];
#endif

    const int tid = threadIdx.x;
    const int w   = tid >> 6;
    const int ln  = tid & 63;
    const int n   = ln & 15;
    const int qd  = ln >> 4;
    const int lr  = ln >> 2;
    const int c8  = (ln & 3) * 8;

    const int bid = blockIdx.x;
    const int qb = bid & 15;
    const int h  = (bid >> 4) & (H_HEADS - 1);
    const int b  = bid >> 8;
    const int q0 = qb * 128;

    const u16* kg = K  + (size_t)b * S_SEQ * 64;
    const u16* vg = VT + (size_t)b * S_SEQ;

    auto stageKV = [&](int p, int s0) {
#pragma unroll
        for (int kb = 0; kb < 2; kb++)
#pragma unroll
            for (int j = 0; j < 2; j++) {
                int row = w * 32 + j * 16 + lr;
                gl_lds16(kg + (size_t)(s0 + row) * 64 + kb * 32 + c8,
                         &ksm[p][kb][row * 32 + c8]);
            }
#pragma unroll
        for (int j = 0; j < 4; j++) {
            int d = j * 16 + lr;
            gl_lds16(vg + (size_t)d * M_ROWS + s0 + w * 32 + c8,
                     &vsm[p][w][d * 32 + c8]);
        }
    };

    // ---- stage Q tile [128][64] into ksm[1] (buf1), stage KV s0=0 into buf0
    if constexpr (sizeof(QT) == 4) {
        const int row = tid >> 1, kb = tid & 1;
        const float* qg = (const float*)Q +
            (size_t)(b * S_SEQ + q0 + row) * E_DIM + h * 64 + kb * 32;
#pragma unroll
        for (int c = 0; c < 4; c++) {
            float4 x = ((const float4*)(qg + c * 8))[0];
            float4 y = ((const float4*)(qg + c * 8))[1];
            *(bf16x8*)&ksm[1][kb][row * 32 + c * 8] = cvt8(x, y);
        }
    } else {
        const u16* qg = (const u16*)Q + (size_t)(b * S_SEQ + q0) * E_DIM + h * 64;
#pragma unroll
        for (int kb = 0; kb < 2; kb++)
#pragma unroll
            for (int j = 0; j < 2; j++) {
                int row = w * 32 + j * 16 + lr;
                gl_lds16(qg + (size_t)row * E_DIM + kb * 32 + c8,
                         &ksm[1][kb][row * 32 + c8]);
            }
    }
    stageKV(0, 0);
    __syncthreads();

    bf16x8 qa[2][2];
#pragma unroll
    for (int mt = 0; mt < 2; mt++)
#pragma unroll
        for (int kb = 0; kb < 2; kb++)
            qa[mt][kb] = *(const bf16x8*)&ksm[1][kb][(w * 32 + mt * 16 + n) * 32 + qd * 8];
    __syncthreads();   // all qa reads done before buf1 is re-staged

    f32x4 acc_o[2][4];
    float lsum[2] = {0.f, 0.f};
#pragma unroll
    for (int mt = 0; mt < 2; mt++)
#pragma unroll
        for (int ntd = 0; ntd < 4; ntd++) acc_o[mt][ntd] = (f32x4){0.f, 0.f, 0.f, 0.f};

    int p = 0;
    for (int s0 = 0; s0 < S_SEQ; s0 += 128) {
        if (s0 + 128 < S_SEQ) stageKV(p ^ 1, s0 + 128);

        // ---- S^T = K Q^T : lane holds t=mt*16+n (col), s=nt*16+qd*4+r (row)
        f32x4 sacc[2][8];
#pragma unroll
        for (int mt = 0; mt < 2; mt++)
#pragma unroll
            for (int nt = 0; nt < 8; nt++) sacc[mt][nt] = (f32x4){0.f, 0.f, 0.f, 0.f};
#pragma unroll
        for (int nt = 0; nt < 8; nt++) {
            int rowk = nt * 16 + n;
#pragma unroll
            for (int kb = 0; kb < 2; kb++) {
                bf16x8 kf = *(const bf16x8*)&ksm[p][kb][rowk * 32 + qd * 8];
                sacc[0][nt] = MFMA32(kf, qa[0][kb], sacc[0][nt]);
                sacc[1][nt] = MFMA32(kf, qa[1][kb], sacc[1][nt]);
            }
        }

        // ---- max-free exp2 softmax + pack P (A-frag orientation for K=16)
        bf16x4 pa[2][8];
#pragma unroll
        for (int mt = 0; mt < 2; mt++) {
            float ls = 0.f;
#pragma unroll
            for (int nt = 0; nt < 8; nt++) {
#pragma unroll
                for (int r = 0; r < 4; r++) {
                    float pv = exp2f(sacc[mt][nt][r]);
                    sacc[mt][nt][r] = pv;
                    ls += pv;
                }
                pa[mt][nt] = pack4(sacc[mt][nt]);
            }
            lsum[mt] += ls;
        }

#if HAVE_MFMA16
        // ---- O += P V via 16x16x16: chunk kk covers s in [kk*16, kk*16+16)
#pragma unroll
        for (int kk = 0; kk < 8; kk++) {
            int c = kk >> 1;
            int off = (kk & 1) * 16 + qd * 4;   // s_local within 32-chunk
#pragma unroll
            for (int ntd = 0; ntd < 4; ntd++) {
                int d = ntd * 16 + n;
                bf16x4 bv = *(const bf16x4*)&vsm[p][c][d * 32 + off];
                acc_o[0][ntd] = MFMA16(pa[0][kk], bv, acc_o[0][ntd]);
                acc_o[1][ntd] = MFMA16(pa[1][kk], bv, acc_o[1][ntd]);
            }
        }
#else
        // ---- fallback: packed-b64 psm round-trip, K=32 PV
#pragma unroll
        for (int mt = 0; mt < 2; mt++)
#pragma unroll
            for (int nt = 0; nt < 8; nt++) {
                int t = mt * 16 + n;
                int lb = nt * 2 + (qd >> 1);
                union { bf16x4 v; uint2 u; } pw; pw.v = pa[mt][nt];
                *(uint2*)&psm[w][t * 128 + ((lb ^ n) * 8) + (qd & 1) * 4] = pw.u;
            }
#pragma unroll
        for (int kb = 0; kb < 4; kb++) {
            bf16x8 paf[2];
#pragma unroll
            for (int mt = 0; mt < 2; mt++) {
                int t = mt * 16 + n;
                paf[mt] = *(const bf16x8*)&psm[w][t * 128 + (((kb * 4 + qd) ^ n) * 8)];
            }
#pragma unroll
            for (int ntd = 0; ntd < 4; ntd++) {
                int d = ntd * 16 + n;
                bf16x8 bv = *(const bf16x8*)&vsm[p][kb][d * 32 + qd * 8];
                acc_o[0][ntd] = MFMA32(paf[0], bv, acc_o[0][ntd]);
                acc_o[1][ntd] = MFMA32(paf[1], bv, acc_o[1][ntd]);
            }
        }
#endif
        p ^= 1;
        __syncthreads();   // drain prefetch; all reads of old buf done
    }

    // ---- epilogue: reduce lsum across quads, divide, scatter
#pragma unroll
    for (int mt = 0; mt < 2; mt++) {
        lsum[mt] += __shfl_xor(lsum[mt], 16);
        lsum[mt] += __shfl_xor(lsum[mt], 32);
    }
#pragma unroll
    for (int mt = 0; mt < 2; mt++)
#pragma unroll
        for (int r = 0; r < 4; r++) {
            float inv = 1.f / __shfl(lsum[mt], qd * 4 + r);
            int grow = b * S_SEQ + q0 + w * 32 + mt * 16 + qd * 4 + r;
#pragma unroll
            for (int ntd = 0; ntd < 4; ntd++) {
                int gcol = h * D_HEAD + ntd * 16 + n;
                O[(size_t)grow * E_DIM + gcol] = f2bf(acc_o[mt][ntd][r] * inv);
            }
        }
}

extern "C" void kernel_launch(void* const* d_in, const int* in_sizes, int n_in,
                              void* d_out, int out_size, void* d_ws, size_t ws_size,
                              hipStream_t stream) {
    const float* query = (const float*)d_in[0];
    const float* key   = (const float*)d_in[1];
    const float* value = (const float*)d_in[2];
    const float* Wq    = (const float*)d_in[3];
    const float* bq    = (const float*)d_in[4];
    const float* Wk    = (const float*)d_in[5];
    const float* bk    = (const float*)d_in[6];
    const float* Wv    = (const float*)d_in[7];
    const float* bv    = (const float*)d_in[8];
    const float* Wo    = (const float*)d_in[9];
    const float* bo    = (const float*)d_in[10];
    float* out = (float*)d_out;

    const int M = M_ROWS;
    const bool big = ws_size >= ((size_t)30 << 20);   // big path needs 29.25 MB

    dim3 blk(256);
    const float scaling = 0.125f * 1.44269504088896f;   // D^-0.5 * log2(e)
    const int NCAST = (2 * E_DIM * E_DIM + 2 * D_HEAD * E_DIM) / 4 / 256;

    // O-proj accumulates atomically into fp32 d_out in both paths.
    hipMemsetAsync(d_out, 0, (size_t)M * E_DIM * 4, stream);

    if (big) {
        // ws: q_f32 16MB | o_bf 8MB | k .5 | vt .5 | wq 2 | wo 2 | wk .125 | wv .125
        float* q_f32 = (float*)d_ws;
        u16* o_bf  = (u16*)(q_f32 + (size_t)M * E_DIM);
        u16* k_bf  = o_bf  + (size_t)M * E_DIM;
        u16* vt_bf = k_bf  + (size_t)M * D_HEAD;
        u16* wq_bf = vt_bf + (size_t)D_HEAD * M;
        u16* wo_bf = wq_bf + (size_t)E_DIM * E_DIM;
        u16* wk_bf = wo_bf + (size_t)E_DIM * E_DIM;
        u16* wv_bf = wk_bf + (size_t)D_HEAD * E_DIM;

        hipMemsetAsync(q_f32, 0, (size_t)M * E_DIM * 4, stream);

        cast_all_kernel<<<dim3(NCAST), blk, 0, stream>>>(
            Wq, Wo, Wk, Wv, wq_bf, wo_bf, wk_bf, wv_bf);

        kv_proj_kernel<<<dim3(M / 64, 2), blk, 0, stream>>>(
            key, value, wk_bf, wv_bf, bk, bv, k_bf, vt_bf, M, E_DIM);

        gemm_splitk_kernel<float, 1><<<dim3(E_DIM / 128, M / 64, 2), blk, 0, stream>>>(
            query, wq_bf, bq, q_f32, M, E_DIM, E_DIM, E_DIM / 2, scaling);

        mqa_attn_kernel<float><<<dim3(B_BATCH * H_HEADS * (S_SEQ / 128)), blk, 0, stream>>>(
            q_f32, k_bf, vt_bf, o_bf);

        gemm_splitk_kernel<u16, 1><<<dim3(E_DIM / 128, M / 64, 2), blk, 0, stream>>>(
            o_bf, wo_bf, bo, out, M, E_DIM, E_DIM, E_DIM / 2, 1.0f);
    } else {
        // fallback ws (13.25 MB, proven): q_bf 8MB (attn O aliases) | k | vt | weights
        u16* q_bf  = (u16*)d_ws;
        u16* k_bf  = q_bf  + (size_t)M * E_DIM;
        u16* vt_bf = k_bf  + (size_t)M * D_HEAD;
        u16* wq_bf = vt_bf + (size_t)D_HEAD * M;
        u16* wo_bf = wq_bf + (size_t)E_DIM * E_DIM;
        u16* wk_bf = wo_bf + (size_t)E_DIM * E_DIM;
        u16* wv_bf = wk_bf + (size_t)D_HEAD * E_DIM;

        cast_all_kernel<<<dim3(NCAST), blk, 0, stream>>>(
            Wq, Wo, Wk, Wv, wq_bf, wo_bf, wk_bf, wv_bf);

        kv_proj_kernel<<<dim3(M / 64, 2), blk, 0, stream>>>(
            key, value, wk_bf, wv_bf, bk, bv, k_bf, vt_bf, M, E_DIM);

        gemm_splitk_kernel<float, 0><<<dim3(E_DIM / 128, M / 64, 1), blk, 0, stream>>>(
            query, wq_bf, bq, q_bf, M, E_DIM, E_DIM, E_DIM, scaling);

        mqa_attn_kernel<u16><<<dim3(B_BATCH * H_HEADS * (S_SEQ / 128)), blk, 0, stream>>>(
            q_bf, k_bf, vt_bf, q_bf);

        gemm_splitk_kernel<u16, 1><<<dim3(E_DIM / 128, M / 64, 2), blk, 0, stream>>>(
            q_bf, wo_bf, bo, out, M, E_DIM, E_DIM, E_DIM / 2, 1.0f);
    }
}

// Round 10
// 262.187 us; speedup vs baseline: 1.2172x; 1.2172x over previous
//
#include <hip/hip_runtime.h>

// MultiQueryAttention: B=2, S=2048, E=1024, H=16, D=64. fp32 I/O.
#define E_DIM  1024
#define H_HEADS 16
#define D_HEAD  64
#define B_BATCH 2
#define S_SEQ  2048
#define M_ROWS (B_BATCH * S_SEQ)   // 4096

typedef unsigned short u16;
typedef unsigned int   u32;
typedef __attribute__((ext_vector_type(8))) short bf16x8;
typedef __attribute__((ext_vector_type(4))) short bf16x4;
typedef __attribute__((ext_vector_type(4))) float f32x4;

#define MFMA32(a, b, c) __builtin_amdgcn_mfma_f32_16x16x32_bf16(a, b, c, 0, 0, 0)

#if __has_builtin(__builtin_amdgcn_mfma_f32_16x16x16bf16_1k)
#define HAVE_MFMA16 1
#define MFMA16(a, b, c) __builtin_amdgcn_mfma_f32_16x16x16bf16_1k(a, b, c, 0, 0, 0)
#else
#define HAVE_MFMA16 0
#endif

__device__ __forceinline__ u16 f2bf(float f) {
    union { float f; u32 i; } x; x.f = f;
    u32 r = x.i + 0x7fffu + ((x.i >> 16) & 1u);   // RNE (finite inputs)
    return (u16)(r >> 16);
}

#if __has_builtin(__builtin_amdgcn_cvt_pk_bf16_f32)
typedef __attribute__((ext_vector_type(2))) __bf16 bfp2;
__device__ __forceinline__ u32 pk2(float a, float b) {
    bfp2 t = __builtin_amdgcn_cvt_pk_bf16_f32(a, b);
    union { bfp2 v; u32 u; } c; c.v = t; return c.u;
}
#else
__device__ __forceinline__ u32 pk2(float a, float b) {
    return (u32)f2bf(a) | ((u32)f2bf(b) << 16);
}
#endif

__device__ __forceinline__ bf16x8 cvt8(const float4& a, const float4& b) {
    union { u32 u[4]; bf16x8 v; } t;
    t.u[0] = pk2(a.x, a.y); t.u[1] = pk2(a.z, a.w);
    t.u[2] = pk2(b.x, b.y); t.u[3] = pk2(b.z, b.w);
    return t.v;
}
__device__ __forceinline__ bf16x4 pack4(const f32x4& v) {
    union { u32 u[2]; bf16x4 w; } t;
    t.u[0] = pk2(v[0], v[1]); t.u[1] = pk2(v[2], v[3]);
    return t.w;
}

// async global->LDS, 16B/lane. LDS dest must be wave-uniform base + lane*16.
__device__ __forceinline__ void gl_lds16(const u16* g, u16* l) {
    __builtin_amdgcn_global_load_lds(
        (const __attribute__((address_space(1))) u32*)g,
        (__attribute__((address_space(3))) u32*)l, 16, 0, 0);
}

// ---------------------------------------------------------------------------
// MFMA GEMM: C = (A @ W^T) * scale + bias*scale.
// Tile 64x64, BK=64 (two 32-k-halves), double-buffered single-barrier loop.
// Grid (N/64, M/64) -> 1024 blocks = 4 blocks/CU at this problem size: the
// extra wave-parallelism + halved barrier count attacks the latency bound.
// A: [M,K] fp32 (reg-cast staging, write-after-compute) or bf16 (gl_lds16).
// W: [N,K] fp32 (reg-cast staging) -- no separate weight-cast dispatch.
// 4 waves = 2x2 of 32x32; frag layouts m89/m101.
// ---------------------------------------------------------------------------
template<typename TA, bool OUT_BF16>
__global__ __launch_bounds__(256, 4) void gemm64_kernel(
    const TA* __restrict__ A, const float* __restrict__ W,
    const float* __restrict__ bias, void* __restrict__ Cv,
    int M, int N, int K, float scale)
{
    __shared__ u16 Asm[2][2][64 * 32];   // [buf][k-half][row*32+c]
    __shared__ u16 Bsm[2][2][64 * 32];

    const int tid = threadIdx.x;
    const int w  = tid >> 6;
    const int ln = tid & 63;
    const int n  = ln & 15;
    const int qd = ln >> 4;
    const int lr = ln >> 2;          // 0..15
    const int c8 = (ln & 3) * 8;     // 16B chunk (elems)
    const int wm = (w & 1) * 32;
    const int wn = (w >> 1) * 32;

    const int m0 = blockIdx.y * 64;
    const int n0 = blockIdx.x * 64;
    const int srow = w * 16 + lr;    // staging row 0..63 (linear in lane)

    f32x4 acc[2][2];
#pragma unroll
    for (int mt = 0; mt < 2; mt++)
#pragma unroll
        for (int nt = 0; nt < 2; nt++) acc[mt][nt] = (f32x4){0.f, 0.f, 0.f, 0.f};

    float4 areg[2][2], breg[2][2];

    auto loadB = [&](int k0) {
#pragma unroll
        for (int kb = 0; kb < 2; kb++) {
            const float* pw = W + (size_t)(n0 + srow) * K + k0 + kb * 32 + c8;
            breg[kb][0] = ((const float4*)pw)[0];
            breg[kb][1] = ((const float4*)pw)[1];
        }
    };
    auto writeB = [&](int p) {
#pragma unroll
        for (int kb = 0; kb < 2; kb++)
            *(bf16x8*)&Bsm[p][kb][srow * 32 + c8] = cvt8(breg[kb][0], breg[kb][1]);
    };
    auto loadA_f32 = [&](int k0) {
#pragma unroll
        for (int kb = 0; kb < 2; kb++) {
            const float* pa = (const float*)A + (size_t)(m0 + srow) * K + k0 + kb * 32 + c8;
            areg[kb][0] = ((const float4*)pa)[0];
            areg[kb][1] = ((const float4*)pa)[1];
        }
    };
    auto writeA_f32 = [&](int p) {
#pragma unroll
        for (int kb = 0; kb < 2; kb++)
            *(bf16x8*)&Asm[p][kb][srow * 32 + c8] = cvt8(areg[kb][0], areg[kb][1]);
    };
    auto stageA_bf16 = [&](int p, int k0) {
#pragma unroll
        for (int kb = 0; kb < 2; kb++)
            gl_lds16((const u16*)A + (size_t)(m0 + srow) * K + k0 + kb * 32 + c8,
                     &Asm[p][kb][srow * 32 + c8]);
    };
    auto compute = [&](int p) {
        bf16x8 af[2][2], bfr[2][2];
#pragma unroll
        for (int t = 0; t < 2; t++)
#pragma unroll
            for (int kb = 0; kb < 2; kb++) {
                af[t][kb]  = *(const bf16x8*)&Asm[p][kb][(wm + t * 16 + n) * 32 + qd * 8];
                bfr[t][kb] = *(const bf16x8*)&Bsm[p][kb][(wn + t * 16 + n) * 32 + qd * 8];
            }
#pragma unroll
        for (int kb = 0; kb < 2; kb++)
#pragma unroll
            for (int mt = 0; mt < 2; mt++)
#pragma unroll
                for (int nt = 0; nt < 2; nt++)
                    acc[mt][nt] = MFMA32(af[mt][kb], bfr[nt][kb], acc[mt][nt]);
    };

    // prologue: tile 0 -> buf 0
    if constexpr (sizeof(TA) == 4) { loadA_f32(0); writeA_f32(0); }
    else                           { stageA_bf16(0, 0); }
    loadB(0); writeB(0);

    int p = 0;
    for (int k0 = 64; k0 < K; k0 += 64) {
        __syncthreads();
        if constexpr (sizeof(TA) == 4) {
            loadA_f32(k0); loadB(k0);       // global loads in flight
            compute(p);                     // overlap with compute
            writeA_f32(p ^ 1); writeB(p ^ 1);
        } else {
            stageA_bf16(p ^ 1, k0);         // async direct-to-LDS
            loadB(k0);
            compute(p);
            writeB(p ^ 1);
        }
        p ^= 1;
    }
    __syncthreads();
    compute(p);

    float bb[2];
#pragma unroll
    for (int nt = 0; nt < 2; nt++) bb[nt] = bias[n0 + wn + nt * 16 + n] * scale;

#pragma unroll
    for (int mt = 0; mt < 2; mt++)
#pragma unroll
        for (int r = 0; r < 4; r++) {
            const int row = m0 + wm + mt * 16 + qd * 4 + r;
#pragma unroll
            for (int nt = 0; nt < 2; nt++) {
                const int col = n0 + wn + nt * 16 + n;
                float v = acc[mt][nt][r] * scale + bb[nt];
                if (OUT_BF16) ((u16*)Cv)[(size_t)row * N + col] = f2bf(v);
                else        ((float*)Cv)[(size_t)row * N + col] = v;
            }
        }
}

// ---------------------------------------------------------------------------
// Fused K/V projection (round-6 LDS-staged form, fp32 W inline cast).
// blockIdx.y==0 -> K proj (row-major), ==1 -> V proj (V^T[64][M]).
// Tile 64x64, BK=32, 2-barrier loop.
// ---------------------------------------------------------------------------
__global__ __launch_bounds__(256) void kv_proj_kernel(
    const float* __restrict__ key, const float* __restrict__ value,
    const float* __restrict__ Wk, const float* __restrict__ Wv,
    const float* __restrict__ bk, const float* __restrict__ bv,
    u16* __restrict__ Kout, u16* __restrict__ VTout, int M, int K)
{
    const bool vproj = (blockIdx.y == 1);
    const float* A    = vproj ? value : key;
    const float* W    = vproj ? Wv : Wk;
    const float* bias = vproj ? bv : bk;

    __shared__ u16 Asm[64 * 32];
    __shared__ u16 Bsm[64 * 32];

    const int tid = threadIdx.x;
    const int w  = tid >> 6;
    const int ln = tid & 63;
    const int n  = ln & 15;
    const int qd = ln >> 4;
    const int wm = (w & 1) * 32;
    const int wn = (w >> 1) * 32;
    const int m0 = blockIdx.x * 64;

    const int srow = tid >> 2;
    const int scol = (tid & 3) * 8;

    f32x4 acc[2][2];
#pragma unroll
    for (int mt = 0; mt < 2; mt++)
#pragma unroll
        for (int nt = 0; nt < 2; nt++) acc[mt][nt] = (f32x4){0.f, 0.f, 0.f, 0.f};

    for (int k0 = 0; k0 < K; k0 += 32) {
        __syncthreads();
        const float* pa = A + (size_t)(m0 + srow) * K + k0 + scol;
        const float* pw = W + (size_t)srow * K + k0 + scol;
        float4 a0 = ((const float4*)pa)[0], a1 = ((const float4*)pa)[1];
        float4 w0 = ((const float4*)pw)[0], w1 = ((const float4*)pw)[1];
        *(bf16x8*)&Asm[srow * 32 + scol] = cvt8(a0, a1);
        *(bf16x8*)&Bsm[srow * 32 + scol] = cvt8(w0, w1);
        __syncthreads();

        bf16x8 af[2], bfr[2];
#pragma unroll
        for (int t = 0; t < 2; t++) {
            af[t]  = *(const bf16x8*)&Asm[(wm + t * 16 + n) * 32 + qd * 8];
            bfr[t] = *(const bf16x8*)&Bsm[(wn + t * 16 + n) * 32 + qd * 8];
        }
#pragma unroll
        for (int mt = 0; mt < 2; mt++)
#pragma unroll
            for (int nt = 0; nt < 2; nt++)
                acc[mt][nt] = MFMA32(af[mt], bfr[nt], acc[mt][nt]);
    }

    if (!vproj) {
#pragma unroll
        for (int mt = 0; mt < 2; mt++)
#pragma unroll
            for (int r = 0; r < 4; r++) {
                const int row = m0 + wm + mt * 16 + qd * 4 + r;
#pragma unroll
                for (int nt = 0; nt < 2; nt++) {
                    const int col = wn + nt * 16 + n;
                    Kout[(size_t)row * 64 + col] = f2bf(acc[mt][nt][r] + bias[col]);
                }
            }
    } else {
#pragma unroll
        for (int mt = 0; mt < 2; mt++)
#pragma unroll
            for (int nt = 0; nt < 2; nt++) {
                const int col = wn + nt * 16 + n;
                const int row0 = m0 + wm + mt * 16 + qd * 4;
                float b4 = bias[col];
                ushort4 pk;
                pk.x = f2bf(acc[mt][nt][0] + b4);
                pk.y = f2bf(acc[mt][nt][1] + b4);
                pk.z = f2bf(acc[mt][nt][2] + b4);
                pk.w = f2bf(acc[mt][nt][3] + b4);
                *(ushort4*)&VTout[(size_t)col * M + row0] = pk;
            }
    }
}

// ---------------------------------------------------------------------------
// MFMA flash MQA attention (round-7 kernel verbatim; proven 69 us), with the
// single safe change __expf -> exp2f (log2e folded into the Q-proj scale).
//  * S^T = K Q^T; P exits in A-frag orientation -> PV via MFMA16 (registers).
//  * Max-free exp2 softmax (scores bounded), lsum reduced in epilogue.
//  * Source-compensated swizzled staging; 32 KB LDS.
// Q: [M,E] bf16 pre-scaled; K: [M,64] bf16; VT: [64,M] bf16.
// O aliases Q (block reads exactly the region it writes).
// ---------------------------------------------------------------------------
__global__ __launch_bounds__(256, 3) void mqa_attn_mfma_kernel(
    const u16* Q, const u16* __restrict__ K,
    const u16* __restrict__ VT, u16* O)
{
    __shared__ u16 ksm[2][128 * 32];   // [k-half][row][32]; Q staged here first
    __shared__ u16 vsm[4][64 * 32];    // [s-chunk32][d][32]
#if !HAVE_MFMA16
    __shared__ u16 psm[4][32 * 128];
#endif

    const int tid = threadIdx.x;
    const int w   = tid >> 6;
    const int ln  = tid & 63;
    const int n   = ln & 15;
    const int qd  = ln >> 4;
    const int lr  = ln >> 2;
    const int blk = ln & 3;
    const int rb  = lr & 3;

    const int bid = blockIdx.x;
    const int qb = bid & 15;
    const int h  = (bid >> 4) & (H_HEADS - 1);
    const int b  = bid >> 8;
    const int q0 = qb * 128;

    {
        const u16* qg = Q + (size_t)(b * S_SEQ + q0) * E_DIM + h * 64;
#pragma unroll
        for (int kb = 0; kb < 2; kb++)
#pragma unroll
            for (int j = 0; j < 2; j++) {
                int row = w * 32 + j * 16 + lr;
                gl_lds16(qg + (size_t)row * E_DIM + kb * 32 + ((blk ^ rb) * 8),
                         &ksm[kb][row * 32 + blk * 8]);
            }
    }
    __syncthreads();

    bf16x8 qa[2][2];
#pragma unroll
    for (int mt = 0; mt < 2; mt++)
#pragma unroll
        for (int kb = 0; kb < 2; kb++) {
            int row = w * 32 + mt * 16 + n;
            qa[mt][kb] = *(const bf16x8*)&ksm[kb][row * 32 + ((qd ^ (n & 3)) * 8)];
        }

    f32x4 acc_o[2][4];
    float lsum[2] = {0.f, 0.f};
#pragma unroll
    for (int mt = 0; mt < 2; mt++)
#pragma unroll
        for (int ntd = 0; ntd < 4; ntd++) acc_o[mt][ntd] = (f32x4){0.f, 0.f, 0.f, 0.f};

    const u16* kg = K  + (size_t)b * S_SEQ * 64;
    const u16* vg = VT + (size_t)b * S_SEQ;

    for (int s0 = 0; s0 < S_SEQ; s0 += 128) {
        __syncthreads();
#pragma unroll
        for (int kb = 0; kb < 2; kb++)
#pragma unroll
            for (int j = 0; j < 2; j++) {
                int row = w * 32 + j * 16 + lr;
                gl_lds16(kg + (size_t)(s0 + row) * 64 + kb * 32 + ((blk ^ rb) * 8),
                         &ksm[kb][row * 32 + blk * 8]);
            }
#pragma unroll
        for (int j = 0; j < 4; j++) {
            int d = j * 16 + lr;
            gl_lds16(vg + (size_t)d * M_ROWS + s0 + w * 32 + ((blk ^ rb) * 8),
                     &vsm[w][d * 32 + blk * 8]);
        }
        __syncthreads();

        // ---- S^T = K Q^T : lane holds t = mt*16+n, s = nt*16 + qd*4 + r
        f32x4 sacc[2][8];
#pragma unroll
        for (int mt = 0; mt < 2; mt++)
#pragma unroll
            for (int nt = 0; nt < 8; nt++) sacc[mt][nt] = (f32x4){0.f, 0.f, 0.f, 0.f};
#pragma unroll
        for (int nt = 0; nt < 8; nt++) {
            int rowk = nt * 16 + n;
#pragma unroll
            for (int kb = 0; kb < 2; kb++) {
                bf16x8 kf = *(const bf16x8*)&ksm[kb][rowk * 32 + ((qd ^ (n & 3)) * 8)];
                sacc[0][nt] = MFMA32(kf, qa[0][kb], sacc[0][nt]);
                sacc[1][nt] = MFMA32(kf, qa[1][kb], sacc[1][nt]);
            }
        }

        // ---- max-free exp2 softmax + pack P into A-frags (registers)
        bf16x4 pa[2][8];
#pragma unroll
        for (int mt = 0; mt < 2; mt++) {
            float ls = 0.f;
#pragma unroll
            for (int nt = 0; nt < 8; nt++) {
#pragma unroll
                for (int r = 0; r < 4; r++) {
                    float pv = exp2f(sacc[mt][nt][r]);
                    sacc[mt][nt][r] = pv;
                    ls += pv;
                }
                pa[mt][nt] = pack4(sacc[mt][nt]);
            }
            lsum[mt] += ls;
        }

#if HAVE_MFMA16
        // ---- O += P V via 16x16x16 (P A-frags direct from registers)
#pragma unroll
        for (int kk = 0; kk < 8; kk++) {
            int c = kk >> 1;
            int lblk = (kk & 1) * 2 + (qd >> 1);
#pragma unroll
            for (int ntd = 0; ntd < 4; ntd++) {
                int d = ntd * 16 + n;
                bf16x4 bv = *(const bf16x4*)
                    &vsm[c][d * 32 + ((lblk ^ (n & 3)) * 8) + (qd & 1) * 4];
                acc_o[0][ntd] = MFMA16(pa[0][kk], bv, acc_o[0][ntd]);
                acc_o[1][ntd] = MFMA16(pa[1][kk], bv, acc_o[1][ntd]);
            }
        }
#else
        // ---- fallback: packed-b64 psm round-trip, K=32 PV
#pragma unroll
        for (int mt = 0; mt < 2; mt++)
#pragma unroll
            for (int nt = 0; nt < 8; nt++) {
                int t = mt * 16 + n;
                int lb = nt * 2 + (qd >> 1);
                union { bf16x4 v; uint2 u; } pw; pw.v = pa[mt][nt];
                *(uint2*)&psm[w][t * 128 + ((lb ^ n) * 8) + (qd & 1) * 4] = pw.u;
            }
#pragma unroll
        for (int kb = 0; kb < 4; kb++) {
            bf16x8 paf[2];
#pragma unroll
            for (int mt = 0; mt < 2; mt++) {
                int t = mt * 16 + n;
                paf[mt] = *(const bf16x8*)&psm[w][t * 128 + (((kb * 4 + qd) ^ n) * 8)];
            }
#pragma unroll
            for (int ntd = 0; ntd < 4; ntd++) {
                int d = ntd * 16 + n;
                bf16x8 bv = *(const bf16x8*)&vsm[kb][d * 32 + ((qd ^ (n & 3)) * 8)];
                acc_o[0][ntd] = MFMA32(paf[0], bv, acc_o[0][ntd]);
                acc_o[1][ntd] = MFMA32(paf[1], bv, acc_o[1][ntd]);
            }
        }
#endif
    }

    // ---- epilogue: reduce lsum across quads, divide, scatter
#pragma unroll
    for (int mt = 0; mt < 2; mt++) {
        lsum[mt] += __shfl_xor(lsum[mt], 16);
        lsum[mt] += __shfl_xor(lsum[mt], 32);
    }
#pragma unroll
    for (int mt = 0; mt < 2; mt++)
#pragma unroll
        for (int r = 0; r < 4; r++) {
            float inv = 1.f / __shfl(lsum[mt], qd * 4 + r);
            int grow = b * S_SEQ + q0 + w * 32 + mt * 16 + qd * 4 + r;
#pragma unroll
            for (int ntd = 0; ntd < 4; ntd++) {
                int gcol = h * D_HEAD + ntd * 16 + n;
                O[(size_t)grow * E_DIM + gcol] = f2bf(acc_o[mt][ntd][r] * inv);
            }
        }
}

extern "C" void kernel_launch(void* const* d_in, const int* in_sizes, int n_in,
                              void* d_out, int out_size, void* d_ws, size_t ws_size,
                              hipStream_t stream) {
    const float* query = (const float*)d_in[0];
    const float* key   = (const float*)d_in[1];
    const float* value = (const float*)d_in[2];
    const float* Wq    = (const float*)d_in[3];
    const float* bq    = (const float*)d_in[4];
    const float* Wk    = (const float*)d_in[5];
    const float* bk    = (const float*)d_in[6];
    const float* Wv    = (const float*)d_in[7];
    const float* bv    = (const float*)d_in[8];
    const float* Wo    = (const float*)d_in[9];
    const float* bo    = (const float*)d_in[10];
    float* out = (float*)d_out;

    const int M = M_ROWS;

    // ws plan (9 MB, within proven-safe 13.25 MB):
    //   q_bf [M][E] 8MB (attn out aliases) | k_bf [M][64] .5 | vt_bf [64][M] .5
    u16* q_bf  = (u16*)d_ws;
    u16* k_bf  = q_bf + (size_t)M * E_DIM;
    u16* vt_bf = k_bf + (size_t)M * D_HEAD;

    dim3 blk(256);
    // D^-0.5 * log2(e): softmax uses exp2
    const float scaling = 0.125f * 1.44269504088896f;

    kv_proj_kernel<<<dim3(M / 64, 2), blk, 0, stream>>>(
        key, value, Wk, Wv, bk, bv, k_bf, vt_bf, M, E_DIM);

    gemm64_kernel<float, true><<<dim3(E_DIM / 64, M / 64), blk, 0, stream>>>(
        query, Wq, bq, q_bf, M, E_DIM, E_DIM, scaling);

    mqa_attn_mfma_kernel<<<dim3(B_BATCH * H_HEADS * (S_SEQ / 128)), blk, 0, stream>>>(
        q_bf, k_bf, vt_bf, q_bf);

    gemm64_kernel<u16, false><<<dim3(E_DIM / 64, M / 64), blk, 0, stream>>>(
        q_bf, Wo, bo, out, M, E_DIM, E_DIM, 1.0f);
}